// Round 9
// baseline (99.404 us; speedup 1.0000x reference)
//
#include <hip/hip_runtime.h>

#define NB 65536
#define D 64
#define SLOPE 0.2f

typedef _Float16 h2f __attribute__((ext_vector_type(2)));

__device__ __forceinline__ h2f as_h2(unsigned x) {
    union { unsigned u; h2f h; } v; v.u = x; return v.h;
}

struct UH { h2f h0, h1, h2, h3; };

__device__ __forceinline__ float dot8(uint4 w, const UH& u, float acc) {
#if __has_builtin(__builtin_amdgcn_fdot2)
    acc = __builtin_amdgcn_fdot2(as_h2(w.x), u.h0, acc, false);
    acc = __builtin_amdgcn_fdot2(as_h2(w.y), u.h1, acc, false);
    acc = __builtin_amdgcn_fdot2(as_h2(w.z), u.h2, acc, false);
    acc = __builtin_amdgcn_fdot2(as_h2(w.w), u.h3, acc, false);
#else
    h2f t0 = as_h2(w.x) * u.h0 + as_h2(w.y) * u.h1;
    h2f t1 = as_h2(w.z) * u.h2 + as_h2(w.w) * u.h3;
    acc += (float)t0.x + (float)t0.y + (float)t1.x + (float)t1.y;
#endif
    return acc;
}

__device__ __forceinline__ float reduce8(float v) {
#pragma unroll
    for (int off = 1; off <= 4; off <<= 1)
        v += __shfl_xor(v, off, 64);
    return v;
}
__device__ __forceinline__ float reduce64(float v) {
#pragma unroll
    for (int off = 1; off <= 32; off <<= 1)
        v += __shfl_xor(v, off, 64);
    return v;
}

__device__ __forceinline__ int lower_bound(const int* __restrict__ seg, int n, int key) {
    int lo = 0, hi = n;
    while (lo < hi) {
        int mid = (lo + hi) >> 1;
        if (seg[mid] < key) lo = mid + 1;
        else hi = mid;
    }
    return lo;
}

// merged pre-pass: fp32 -> f16 table convert (table at ws+0, rows 128B-aligned) + offsets
__global__ __launch_bounds__(256)
void prepass(const float2* __restrict__ ef2, unsigned* __restrict__ eh, int n2,
             const int* __restrict__ a_seg, int Ta, int* __restrict__ offs_a,
             const int* __restrict__ c_seg, int Tc, int* __restrict__ offs_c)
{
    const int t = blockIdx.x * blockDim.x + threadIdx.x;
    if (t < n2) {
        float2 v = ef2[t];
        h2f h = { (_Float16)v.x, (_Float16)v.y };
        union { h2f h; unsigned u; } cv; cv.h = h;
        eh[t] = cv.u;
    }
    if (t < Ta) {
        int s = a_seg[t];
        if (t == 0) offs_a[0] = 0;
        else if (a_seg[t - 1] != s) offs_a[s] = t;
        if (t == Ta - 1) offs_a[s + 1] = Ta;
    }
    if (t < Tc) {
        int s = c_seg[t];
        if (t == 0) offs_c[0] = 0;
        else if (c_seg[t - 1] != s) offs_c[s] = t;
        if (t == Tc - 1) offs_c[s + 1] = Tc;
    }
}

// wave-pair kernel: 2 waves per row; each wave does a contiguous half of BOTH segments
__global__ __launch_bounds__(256)
void aspect_pair(const int* __restrict__ user_id,
                 const int* __restrict__ a_ids, const int* __restrict__ offs_a,
                 const int* __restrict__ c_ids, const int* __restrict__ offs_c,
                 const float* __restrict__ user_factors,
                 const uint4* __restrict__ efh,    // f16 table, 8 uint4 per row
                 const float* __restrict__ relation_k,
                 float* __restrict__ out)
{
    const int tid  = threadIdx.x;
    const int wib  = tid >> 6;         // wave in block 0..3
    const int lane = tid & 63;
    const int pair = wib >> 1;         // row slot 0..1
    const int half = wib & 1;          // segment half 0..1
    const int b    = blockIdx.x * 2 + pair;
    const int r = lane >> 3;           // row subgroup 0..7
    const int c = lane & 7;            // dim chunk 0..7

    const int uid = user_id[b];
    const float4 ua = reinterpret_cast<const float4*>(user_factors)[uid * 16 + 2 * c];
    const float4 ub = reinterpret_cast<const float4*>(user_factors)[uid * 16 + 2 * c + 1];

    UH uh;
    uh.h0 = h2f{ (_Float16)ua.x, (_Float16)ua.y };
    uh.h1 = h2f{ (_Float16)ua.z, (_Float16)ua.w };
    uh.h2 = h2f{ (_Float16)ub.x, (_Float16)ub.y };
    uh.h3 = h2f{ (_Float16)ub.z, (_Float16)ub.w };

    const int sa = offs_a[b], ea = offs_a[b + 1];
    const int sc = offs_c[b], ec = offs_c[b + 1];

    // contiguous halves (balanced: each wave gets ~half of artists + ~half of categories)
    const int ma = sa + ((ea - sa + 1) >> 1);
    const int mc = sc + ((ec - sc + 1) >> 1);
    const int s_a = half ? ma : sa, e_a = half ? ea : ma;
    const int s_c = half ? mc : sc, e_c = half ? ec : mc;

    auto gather = [&](const int* __restrict__ ids, int s, int e) -> float {
        float acc = 0.f;
        int t = s;
        for (; t + 16 <= e; t += 16) {
            const int id0 = ids[t + r];
            const int id1 = ids[t + 8 + r];
            const uint4 w0 = efh[id0 * 8 + c];
            const uint4 w1 = efh[id1 * 8 + c];
            acc = dot8(w0, uh, acc);
            acc = dot8(w1, uh, acc);
        }
        if (t + r < e) {
            const uint4 w0 = efh[ids[t + r] * 8 + c];
            acc = dot8(w0, uh, acc);
        }
        t += 8;
        if (t < e && t + r < e) {
            const uint4 w1 = efh[ids[t + r] * 8 + c];
            acc = dot8(w1, uh, acc);
        }
        return reduce64(acc);
    };

    const float pa = gather(a_ids, s_a, e_a);
    const float pc = gather(c_ids, s_c, e_c);

    __shared__ float xch[4][2];
    if (lane == 0) { xch[wib][0] = pa; xch[wib][1] = pc; }
    __syncthreads();

    if (half == 0) {
        // ---- logits + softmax (3-way) on the writer wave only ----
        float p0 = 0.f, p1 = 0.f, p2 = 0.f;
        {
            const float uv[8] = {ua.x, ua.y, ua.z, ua.w, ub.x, ub.y, ub.z, ub.w};
#pragma unroll
            for (int j = 0; j < 8; ++j) {
                const int row = 8 * c + j;
                p0 += uv[j] * relation_k[row * 3 + 0];
                p1 += uv[j] * relation_k[row * 3 + 1];
                p2 += uv[j] * relation_k[row * 3 + 2];
            }
        }
        float l0 = reduce8(p0), l1 = reduce8(p1), l2 = reduce8(p2);
        l0 = l0 > 0.f ? l0 : SLOPE * l0;
        l1 = l1 > 0.f ? l1 : SLOPE * l1;
        l2 = l2 > 0.f ? l2 : SLOPE * l2;
        const float m  = fmaxf(l0, fmaxf(l1, l2));
        const float e0 = __expf(l0 - m);
        const float e1 = __expf(l1 - m);
        const float e2 = __expf(l2 - m);
        const float inv = 1.0f / (e0 + e1 + e2);
        const float s0 = e0 * inv, s1 = e1 * inv, s2 = e2 * inv;

        const float c_a = (xch[2 * pair][0] + xch[2 * pair + 1][0]) / (float)(ea - sa);
        const float c_c = (xch[2 * pair][1] + xch[2 * pair + 1][1]) / (float)(ec - sc);
        const float pred = (c_a * s0 + c_c * s1) / (s0 + s1);

        if (lane == 0) {
            out[b]          = pred;
            out[4 * NB + b] = c_a;
            out[5 * NB + b] = c_c;
        }
        if (lane < 3) {
            const float sv = (lane == 0) ? s0 : ((lane == 1) ? s1 : s2);
            out[NB + 3 * b + lane] = sv;
        }
    }
}

// fallback (no workspace): bsearch + fp32, one wave per row
__global__ __launch_bounds__(256)
void aspect_fallback(const int* __restrict__ user_id,
                     const int* __restrict__ a_ids, const int* __restrict__ a_seg, int Ta,
                     const int* __restrict__ c_ids, const int* __restrict__ c_seg, int Tc,
                     const float* __restrict__ user_factors,
                     const float4* __restrict__ ef4,
                     const float* __restrict__ relation_k,
                     float* __restrict__ out)
{
    const int b    = blockIdx.x * 4 + (threadIdx.x >> 6);
    const int lane = threadIdx.x & 63;
    const int g = lane >> 4, k = lane & 15;

    const int uid = user_id[b];
    const float4 u4 = reinterpret_cast<const float4*>(user_factors)[uid * 16 + k];

    float p0 = 0.f, p1 = 0.f, p2 = 0.f;
    {
        const float uv[4] = {u4.x, u4.y, u4.z, u4.w};
#pragma unroll
        for (int j = 0; j < 4; ++j) {
            const int row = 4 * k + j;
            p0 += uv[j] * relation_k[row * 3 + 0];
            p1 += uv[j] * relation_k[row * 3 + 1];
            p2 += uv[j] * relation_k[row * 3 + 2];
        }
    }
#pragma unroll
    for (int off = 1; off <= 8; off <<= 1) {
        p0 += __shfl_xor(p0, off, 64);
        p1 += __shfl_xor(p1, off, 64);
        p2 += __shfl_xor(p2, off, 64);
    }
    float l0 = p0 > 0.f ? p0 : SLOPE * p0;
    float l1 = p1 > 0.f ? p1 : SLOPE * p1;
    float l2 = p2 > 0.f ? p2 : SLOPE * p2;
    const float m  = fmaxf(l0, fmaxf(l1, l2));
    const float e0 = __expf(l0 - m), e1 = __expf(l1 - m), e2 = __expf(l2 - m);
    const float inv = 1.0f / (e0 + e1 + e2);
    const float s0 = e0 * inv, s1 = e1 * inv, s2 = e2 * inv;

    auto gd = [&](const int* __restrict__ ids, int s, int e) -> float {
        float ax = 0.f, ay = 0.f, az = 0.f, aw = 0.f;
        int t = s;
        for (; t + 4 <= e; t += 4) {
            const float4 v0 = ef4[ids[t + g] * 16 + k];
            ax += v0.x; ay += v0.y; az += v0.z; aw += v0.w;
        }
        if (t + g < e) {
            const float4 v0 = ef4[ids[t + g] * 16 + k];
            ax += v0.x; ay += v0.y; az += v0.z; aw += v0.w;
        }
        return reduce64(ax * u4.x + ay * u4.y + az * u4.z + aw * u4.w);
    };

    const int sa = lower_bound(a_seg, Ta, b), ea = lower_bound(a_seg, Ta, b + 1);
    const int sc = lower_bound(c_seg, Tc, b), ec = lower_bound(c_seg, Tc, b + 1);
    const float c_a = gd(a_ids, sa, ea) / (float)(ea - sa);
    const float c_c = gd(c_ids, sc, ec) / (float)(ec - sc);
    const float pred = (c_a * s0 + c_c * s1) / (s0 + s1);

    if (lane == 0) {
        out[b]          = pred;
        out[4 * NB + b] = c_a;
        out[5 * NB + b] = c_c;
    }
    if (lane < 3) {
        const float sv = (lane == 0) ? s0 : ((lane == 1) ? s1 : s2);
        out[NB + 3 * b + lane] = sv;
    }
}

extern "C" void kernel_launch(void* const* d_in, const int* in_sizes, int n_in,
                              void* d_out, int out_size, void* d_ws, size_t ws_size,
                              hipStream_t stream) {
    const int*   user_id        = (const int*)d_in[0];
    const int*   artists_ids    = (const int*)d_in[1];
    const int*   artists_seg    = (const int*)d_in[2];
    const int*   categories_ids = (const int*)d_in[3];
    const int*   categories_seg = (const int*)d_in[4];
    const float* user_factors   = (const float*)d_in[5];
    const float* entity_factors = (const float*)d_in[6];
    const float* relation_k     = (const float*)d_in[7];
    float* out = (float*)d_out;

    const int Ta = in_sizes[1];
    const int Tc = in_sizes[3];
    const int n_ent_elems = in_sizes[6];    // N_ENTITY * D
    const int n2 = n_ent_elems / 2;

    // layout: [f16 table at ws+0 (rows 128B-aligned)] [offs_a] [offs_c]
    const size_t table_bytes = (size_t)n_ent_elems * 2;
    const size_t offs_bytes  = (size_t)2 * (NB + 1) * sizeof(int);

    if (ws_size >= table_bytes + offs_bytes) {
        unsigned* efh    = (unsigned*)d_ws;
        int*      offs_a = (int*)((unsigned char*)d_ws + table_bytes);
        int*      offs_c = offs_a + (NB + 1);
        int prep_n = n2 > Ta ? n2 : Ta;
        if (Tc > prep_n) prep_n = Tc;
        prepass<<<(prep_n + 255) / 256, 256, 0, stream>>>(
            (const float2*)entity_factors, efh, n2,
            artists_seg, Ta, offs_a,
            categories_seg, Tc, offs_c);
        // 2 waves per row, 4 waves/block -> 2 rows/block
        aspect_pair<<<NB / 2, 256, 0, stream>>>(user_id,
            artists_ids, offs_a, categories_ids, offs_c,
            user_factors, (const uint4*)efh, relation_k, out);
    } else {
        aspect_fallback<<<NB / 4, 256, 0, stream>>>(user_id,
            artists_ids, artists_seg, Ta,
            categories_ids, categories_seg, Tc,
            user_factors, (const float4*)entity_factors, relation_k, out);
    }
}

// Round 10
// 88.934 us; speedup vs baseline: 1.1177x; 1.1177x over previous
//
#include <hip/hip_runtime.h>

#define NB 65536
#define D 64
#define SLOPE 0.2f

typedef _Float16 h2f __attribute__((ext_vector_type(2)));

__device__ __forceinline__ h2f as_h2(unsigned x) {
    union { unsigned u; h2f h; } v; v.u = x; return v.h;
}

struct UH { h2f h0, h1, h2, h3; };

__device__ __forceinline__ float dot8(uint4 w, const UH& u, float acc) {
#if __has_builtin(__builtin_amdgcn_fdot2)
    acc = __builtin_amdgcn_fdot2(as_h2(w.x), u.h0, acc, false);
    acc = __builtin_amdgcn_fdot2(as_h2(w.y), u.h1, acc, false);
    acc = __builtin_amdgcn_fdot2(as_h2(w.z), u.h2, acc, false);
    acc = __builtin_amdgcn_fdot2(as_h2(w.w), u.h3, acc, false);
#else
    h2f t0 = as_h2(w.x) * u.h0 + as_h2(w.y) * u.h1;
    h2f t1 = as_h2(w.z) * u.h2 + as_h2(w.w) * u.h3;
    acc += (float)t0.x + (float)t0.y + (float)t1.x + (float)t1.y;
#endif
    return acc;
}

__device__ __forceinline__ float reduce8(float v) {
#pragma unroll
    for (int off = 1; off <= 4; off <<= 1)
        v += __shfl_xor(v, off, 64);
    return v;
}
__device__ __forceinline__ float reduce64(float v) {
#pragma unroll
    for (int off = 1; off <= 32; off <<= 1)
        v += __shfl_xor(v, off, 64);
    return v;
}

__device__ __forceinline__ int lower_bound(const int* __restrict__ seg, int n, int key) {
    int lo = 0, hi = n;
    while (lo < hi) {
        int mid = (lo + hi) >> 1;
        if (seg[mid] < key) lo = mid + 1;
        else hi = mid;
    }
    return lo;
}

// merged pre-pass: fp32 -> f16 table convert (table at ws+0, rows 128B-aligned) + offsets
__global__ __launch_bounds__(256)
void prepass(const float2* __restrict__ ef2, unsigned* __restrict__ eh, int n2,
             const int* __restrict__ a_seg, int Ta, int* __restrict__ offs_a,
             const int* __restrict__ c_seg, int Tc, int* __restrict__ offs_c)
{
    const int t = blockIdx.x * blockDim.x + threadIdx.x;
    if (t < n2) {
        float2 v = ef2[t];
        h2f h = { (_Float16)v.x, (_Float16)v.y };
        union { h2f h; unsigned u; } cv; cv.h = h;
        eh[t] = cv.u;
    }
    if (t < Ta) {
        int s = a_seg[t];
        if (t == 0) offs_a[0] = 0;
        else if (a_seg[t - 1] != s) offs_a[s] = t;
        if (t == Ta - 1) offs_a[s + 1] = Ta;
    }
    if (t < Tc) {
        int s = c_seg[t];
        if (t == 0) offs_c[0] = 0;
        else if (c_seg[t - 1] != s) offs_c[s] = t;
        if (t == Tc - 1) offs_c[s + 1] = Tc;
    }
}

// one wave per row; both segments fused into one stream, 4 gather-groups in flight
__global__ __launch_bounds__(256)
void aspect_fused(const int* __restrict__ user_id,
                  const int* __restrict__ a_ids, const int* __restrict__ offs_a,
                  const int* __restrict__ c_ids, const int* __restrict__ offs_c,
                  const float* __restrict__ user_factors,
                  const uint4* __restrict__ efh,    // f16 table, 8 uint4 per row
                  const float* __restrict__ relation_k,
                  float* __restrict__ out)
{
    const int b    = blockIdx.x * 4 + (threadIdx.x >> 6);
    const int lane = threadIdx.x & 63;
    const int r = lane >> 3;     // row subgroup 0..7
    const int c = lane & 7;      // dim chunk 0..7 (dims 8c..8c+7)

    const int uid = user_id[b];
    const float4 ua = reinterpret_cast<const float4*>(user_factors)[uid * 16 + 2 * c];
    const float4 ub = reinterpret_cast<const float4*>(user_factors)[uid * 16 + 2 * c + 1];

    // ---- logits + softmax (3-way) ----
    float p0 = 0.f, p1 = 0.f, p2 = 0.f;
    {
        const float uv[8] = {ua.x, ua.y, ua.z, ua.w, ub.x, ub.y, ub.z, ub.w};
#pragma unroll
        for (int j = 0; j < 8; ++j) {
            const int row = 8 * c + j;
            p0 += uv[j] * relation_k[row * 3 + 0];
            p1 += uv[j] * relation_k[row * 3 + 1];
            p2 += uv[j] * relation_k[row * 3 + 2];
        }
    }
    float l0 = reduce8(p0), l1 = reduce8(p1), l2 = reduce8(p2);
    l0 = l0 > 0.f ? l0 : SLOPE * l0;
    l1 = l1 > 0.f ? l1 : SLOPE * l1;
    l2 = l2 > 0.f ? l2 : SLOPE * l2;
    const float m  = fmaxf(l0, fmaxf(l1, l2));
    const float e0 = __expf(l0 - m);
    const float e1 = __expf(l1 - m);
    const float e2 = __expf(l2 - m);
    const float inv = 1.0f / (e0 + e1 + e2);
    const float s0 = e0 * inv, s1 = e1 * inv, s2 = e2 * inv;

    const int sa = offs_a[b], ea = offs_a[b + 1];
    const int sc = offs_c[b], ec = offs_c[b + 1];
    const int na = ea - sa;
    const int nc = ec - sc;
    const int n  = na + nc;

    UH uh;
    uh.h0 = h2f{ (_Float16)ua.x, (_Float16)ua.y };
    uh.h1 = h2f{ (_Float16)ua.z, (_Float16)ua.w };
    uh.h2 = h2f{ (_Float16)ub.x, (_Float16)ub.y };
    uh.h3 = h2f{ (_Float16)ub.z, (_Float16)ub.w };

    // fused gather over combined stream: 32 rows / iter, 4 predicated 8-row groups
    float accA = 0.f, accC = 0.f;
    for (int t = 0; t < n; t += 32) {
#pragma unroll
        for (int jj = 0; jj < 4; ++jj) {
            const int i = t + 8 * jj + r;
            if (i < n) {
                const bool isA = i < na;
                const int id = isA ? a_ids[sa + i] : c_ids[sc + i - na];
                const uint4 w = efh[id * 8 + c];
                const float d = dot8(w, uh, 0.f);
                accA += isA ? d : 0.f;
                accC += isA ? 0.f : d;
            }
        }
    }

    const float c_a = reduce64(accA) / (float)na;
    const float c_c = reduce64(accC) / (float)nc;

    const float pred = (c_a * s0 + c_c * s1) / (s0 + s1);

    if (lane == 0) {
        out[b]          = pred;
        out[4 * NB + b] = c_a;
        out[5 * NB + b] = c_c;
    }
    if (lane < 3) {
        const float sv = (lane == 0) ? s0 : ((lane == 1) ? s1 : s2);
        out[NB + 3 * b + lane] = sv;
    }
}

// fallback (no workspace): bsearch + fp32, one wave per row
__global__ __launch_bounds__(256)
void aspect_fallback(const int* __restrict__ user_id,
                     const int* __restrict__ a_ids, const int* __restrict__ a_seg, int Ta,
                     const int* __restrict__ c_ids, const int* __restrict__ c_seg, int Tc,
                     const float* __restrict__ user_factors,
                     const float4* __restrict__ ef4,
                     const float* __restrict__ relation_k,
                     float* __restrict__ out)
{
    const int b    = blockIdx.x * 4 + (threadIdx.x >> 6);
    const int lane = threadIdx.x & 63;
    const int g = lane >> 4, k = lane & 15;

    const int uid = user_id[b];
    const float4 u4 = reinterpret_cast<const float4*>(user_factors)[uid * 16 + k];

    float p0 = 0.f, p1 = 0.f, p2 = 0.f;
    {
        const float uv[4] = {u4.x, u4.y, u4.z, u4.w};
#pragma unroll
        for (int j = 0; j < 4; ++j) {
            const int row = 4 * k + j;
            p0 += uv[j] * relation_k[row * 3 + 0];
            p1 += uv[j] * relation_k[row * 3 + 1];
            p2 += uv[j] * relation_k[row * 3 + 2];
        }
    }
#pragma unroll
    for (int off = 1; off <= 8; off <<= 1) {
        p0 += __shfl_xor(p0, off, 64);
        p1 += __shfl_xor(p1, off, 64);
        p2 += __shfl_xor(p2, off, 64);
    }
    float l0 = p0 > 0.f ? p0 : SLOPE * p0;
    float l1 = p1 > 0.f ? p1 : SLOPE * p1;
    float l2 = p2 > 0.f ? p2 : SLOPE * p2;
    const float m  = fmaxf(l0, fmaxf(l1, l2));
    const float e0 = __expf(l0 - m), e1 = __expf(l1 - m), e2 = __expf(l2 - m);
    const float inv = 1.0f / (e0 + e1 + e2);
    const float s0 = e0 * inv, s1 = e1 * inv, s2 = e2 * inv;

    auto gd = [&](const int* __restrict__ ids, int s, int e) -> float {
        float ax = 0.f, ay = 0.f, az = 0.f, aw = 0.f;
        int t = s;
        for (; t + 4 <= e; t += 4) {
            const float4 v0 = ef4[ids[t + g] * 16 + k];
            ax += v0.x; ay += v0.y; az += v0.z; aw += v0.w;
        }
        if (t + g < e) {
            const float4 v0 = ef4[ids[t + g] * 16 + k];
            ax += v0.x; ay += v0.y; az += v0.z; aw += v0.w;
        }
        return reduce64(ax * u4.x + ay * u4.y + az * u4.z + aw * u4.w);
    };

    const int sa = lower_bound(a_seg, Ta, b), ea = lower_bound(a_seg, Ta, b + 1);
    const int sc = lower_bound(c_seg, Tc, b), ec = lower_bound(c_seg, Tc, b + 1);
    const float c_a = gd(a_ids, sa, ea) / (float)(ea - sa);
    const float c_c = gd(c_ids, sc, ec) / (float)(ec - sc);
    const float pred = (c_a * s0 + c_c * s1) / (s0 + s1);

    if (lane == 0) {
        out[b]          = pred;
        out[4 * NB + b] = c_a;
        out[5 * NB + b] = c_c;
    }
    if (lane < 3) {
        const float sv = (lane == 0) ? s0 : ((lane == 1) ? s1 : s2);
        out[NB + 3 * b + lane] = sv;
    }
}

extern "C" void kernel_launch(void* const* d_in, const int* in_sizes, int n_in,
                              void* d_out, int out_size, void* d_ws, size_t ws_size,
                              hipStream_t stream) {
    const int*   user_id        = (const int*)d_in[0];
    const int*   artists_ids    = (const int*)d_in[1];
    const int*   artists_seg    = (const int*)d_in[2];
    const int*   categories_ids = (const int*)d_in[3];
    const int*   categories_seg = (const int*)d_in[4];
    const float* user_factors   = (const float*)d_in[5];
    const float* entity_factors = (const float*)d_in[6];
    const float* relation_k     = (const float*)d_in[7];
    float* out = (float*)d_out;

    const int Ta = in_sizes[1];
    const int Tc = in_sizes[3];
    const int n_ent_elems = in_sizes[6];    // N_ENTITY * D
    const int n2 = n_ent_elems / 2;

    // layout: [f16 table at ws+0 (rows 128B-aligned)] [offs_a] [offs_c]
    const size_t table_bytes = (size_t)n_ent_elems * 2;
    const size_t offs_bytes  = (size_t)2 * (NB + 1) * sizeof(int);

    if (ws_size >= table_bytes + offs_bytes) {
        unsigned* efh    = (unsigned*)d_ws;
        int*      offs_a = (int*)((unsigned char*)d_ws + table_bytes);
        int*      offs_c = offs_a + (NB + 1);
        int prep_n = n2 > Ta ? n2 : Ta;
        if (Tc > prep_n) prep_n = Tc;
        prepass<<<(prep_n + 255) / 256, 256, 0, stream>>>(
            (const float2*)entity_factors, efh, n2,
            artists_seg, Ta, offs_a,
            categories_seg, Tc, offs_c);
        aspect_fused<<<NB / 4, 256, 0, stream>>>(user_id,
            artists_ids, offs_a, categories_ids, offs_c,
            user_factors, (const uint4*)efh, relation_k, out);
    } else {
        aspect_fallback<<<NB / 4, 256, 0, stream>>>(user_id,
            artists_ids, artists_seg, Ta,
            categories_ids, categories_seg, Tc,
            user_factors, (const float4*)entity_factors, relation_k, out);
    }
}

// Round 11
// 78.403 us; speedup vs baseline: 1.2679x; 1.1343x over previous
//
#include <hip/hip_runtime.h>

#define NB 65536
#define D 64
#define SLOPE 0.2f
#define GA 10   // max artists groups: ceil(79/8)
#define GC 3    // max categories groups: ceil(19/8)

typedef _Float16 h2f __attribute__((ext_vector_type(2)));

__device__ __forceinline__ h2f as_h2(unsigned x) {
    union { unsigned u; h2f h; } v; v.u = x; return v.h;
}

struct UH { h2f h0, h1, h2, h3; };

__device__ __forceinline__ float dot8(uint4 w, const UH& u, float acc) {
#if __has_builtin(__builtin_amdgcn_fdot2)
    acc = __builtin_amdgcn_fdot2(as_h2(w.x), u.h0, acc, false);
    acc = __builtin_amdgcn_fdot2(as_h2(w.y), u.h1, acc, false);
    acc = __builtin_amdgcn_fdot2(as_h2(w.z), u.h2, acc, false);
    acc = __builtin_amdgcn_fdot2(as_h2(w.w), u.h3, acc, false);
#else
    h2f t0 = as_h2(w.x) * u.h0 + as_h2(w.y) * u.h1;
    h2f t1 = as_h2(w.z) * u.h2 + as_h2(w.w) * u.h3;
    acc += (float)t0.x + (float)t0.y + (float)t1.x + (float)t1.y;
#endif
    return acc;
}

__device__ __forceinline__ float reduce8(float v) {
#pragma unroll
    for (int off = 1; off <= 4; off <<= 1)
        v += __shfl_xor(v, off, 64);
    return v;
}
__device__ __forceinline__ float reduce64(float v) {
#pragma unroll
    for (int off = 1; off <= 32; off <<= 1)
        v += __shfl_xor(v, off, 64);
    return v;
}

__device__ __forceinline__ int lower_bound(const int* __restrict__ seg, int n, int key) {
    int lo = 0, hi = n;
    while (lo < hi) {
        int mid = (lo + hi) >> 1;
        if (seg[mid] < key) lo = mid + 1;
        else hi = mid;
    }
    return lo;
}

// merged pre-pass: fp32 -> f16 table convert (table at ws+0, rows 128B-aligned) + offsets
__global__ __launch_bounds__(256)
void prepass(const float2* __restrict__ ef2, unsigned* __restrict__ eh, int n2,
             const int* __restrict__ a_seg, int Ta, int* __restrict__ offs_a,
             const int* __restrict__ c_seg, int Tc, int* __restrict__ offs_c)
{
    const int t = blockIdx.x * blockDim.x + threadIdx.x;
    if (t < n2) {
        float2 v = ef2[t];
        h2f h = { (_Float16)v.x, (_Float16)v.y };
        union { h2f h; unsigned u; } cv; cv.h = h;
        eh[t] = cv.u;
    }
    if (t < Ta) {
        int s = a_seg[t];
        if (t == 0) offs_a[0] = 0;
        else if (a_seg[t - 1] != s) offs_a[s] = t;
        if (t == Ta - 1) offs_a[s + 1] = Ta;
    }
    if (t < Tc) {
        int s = c_seg[t];
        if (t == 0) offs_c[0] = 0;
        else if (c_seg[t - 1] != s) offs_c[s] = t;
        if (t == Tc - 1) offs_c[s + 1] = Tc;
    }
}

// one wave per row; batch-issue ALL id loads, then ALL row gathers, then all dots.
// Group predicates (g < Ga) are wave-uniform -> scalar branches, no exec divergence.
// Per-lane tails: index clamped to segment end (dup line, L1-hit) + cndmask on the dot.
__global__ __launch_bounds__(256)
void aspect_deep(const int* __restrict__ user_id,
                 const int* __restrict__ a_ids, const int* __restrict__ offs_a,
                 const int* __restrict__ c_ids, const int* __restrict__ offs_c,
                 const float* __restrict__ user_factors,
                 const uint4* __restrict__ efh,    // f16 table, 8 uint4 per row
                 const float* __restrict__ relation_k,
                 float* __restrict__ out)
{
    const int b    = blockIdx.x * 4 + (threadIdx.x >> 6);
    const int lane = threadIdx.x & 63;
    const int r = lane >> 3;     // row subgroup 0..7
    const int c = lane & 7;      // dim chunk 0..7 (dims 8c..8c+7)

    const int uid = user_id[b];
    const float4 ua = reinterpret_cast<const float4*>(user_factors)[uid * 16 + 2 * c];
    const float4 ub = reinterpret_cast<const float4*>(user_factors)[uid * 16 + 2 * c + 1];

    const int sa = offs_a[b], ea = offs_a[b + 1];
    const int sc = offs_c[b], ec = offs_c[b + 1];
    const int na = ea - sa, nc = ec - sc;
    const int Ga = (na + 7) >> 3;   // 1..GA (wave-uniform)
    const int Gc = (nc + 7) >> 3;   // 1..GC (wave-uniform)

    // ---- batch 1: all id loads (independent, issue back-to-back) ----
    int ida[GA], idc[GC];
#pragma unroll
    for (int g = 0; g < GA; ++g)
        if (g < Ga) ida[g] = a_ids[sa + min(8 * g + r, na - 1)];
#pragma unroll
    for (int g = 0; g < GC; ++g)
        if (g < Gc) idc[g] = c_ids[sc + min(8 * g + r, nc - 1)];

    // ---- overlap id-load latency with logits + softmax (pure VALU) ----
    float p0 = 0.f, p1 = 0.f, p2 = 0.f;
    {
        const float uv[8] = {ua.x, ua.y, ua.z, ua.w, ub.x, ub.y, ub.z, ub.w};
#pragma unroll
        for (int j = 0; j < 8; ++j) {
            const int row = 8 * c + j;
            p0 += uv[j] * relation_k[row * 3 + 0];
            p1 += uv[j] * relation_k[row * 3 + 1];
            p2 += uv[j] * relation_k[row * 3 + 2];
        }
    }
    float l0 = reduce8(p0), l1 = reduce8(p1), l2 = reduce8(p2);
    l0 = l0 > 0.f ? l0 : SLOPE * l0;
    l1 = l1 > 0.f ? l1 : SLOPE * l1;
    l2 = l2 > 0.f ? l2 : SLOPE * l2;
    const float m  = fmaxf(l0, fmaxf(l1, l2));
    const float e0 = __expf(l0 - m);
    const float e1 = __expf(l1 - m);
    const float e2 = __expf(l2 - m);
    const float inv = 1.0f / (e0 + e1 + e2);
    const float s0 = e0 * inv, s1 = e1 * inv, s2 = e2 * inv;

    UH uh;
    uh.h0 = h2f{ (_Float16)ua.x, (_Float16)ua.y };
    uh.h1 = h2f{ (_Float16)ua.z, (_Float16)ua.w };
    uh.h2 = h2f{ (_Float16)ub.x, (_Float16)ub.y };
    uh.h3 = h2f{ (_Float16)ub.z, (_Float16)ub.w };

    // ---- batch 2: all row gathers (up to 13 misses in flight) ----
    uint4 wa[GA], wc[GC];
#pragma unroll
    for (int g = 0; g < GA; ++g)
        if (g < Ga) wa[g] = efh[(unsigned)ida[g] * 8 + c];
#pragma unroll
    for (int g = 0; g < GC; ++g)
        if (g < Gc) wc[g] = efh[(unsigned)idc[g] * 8 + c];

    // ---- batch 3: dots, tail lanes zeroed ----
    float accA = 0.f, accC = 0.f;
#pragma unroll
    for (int g = 0; g < GA; ++g)
        if (g < Ga) {
            const float d = dot8(wa[g], uh, 0.f);
            accA += (8 * g + r < na) ? d : 0.f;
        }
#pragma unroll
    for (int g = 0; g < GC; ++g)
        if (g < Gc) {
            const float d = dot8(wc[g], uh, 0.f);
            accC += (8 * g + r < nc) ? d : 0.f;
        }

    // overflow safety (dead for this generator: na<=79, nc<=19)
    for (int i = 8 * GA + r; i < na; i += 8)
        accA = dot8(efh[(unsigned)a_ids[sa + i] * 8 + c], uh, accA);
    for (int i = 8 * GC + r; i < nc; i += 8)
        accC = dot8(efh[(unsigned)c_ids[sc + i] * 8 + c], uh, accC);

    const float c_a = reduce64(accA) / (float)na;
    const float c_c = reduce64(accC) / (float)nc;

    const float pred = (c_a * s0 + c_c * s1) / (s0 + s1);

    if (lane == 0) {
        out[b]          = pred;
        out[4 * NB + b] = c_a;
        out[5 * NB + b] = c_c;
    }
    if (lane < 3) {
        const float sv = (lane == 0) ? s0 : ((lane == 1) ? s1 : s2);
        out[NB + 3 * b + lane] = sv;
    }
}

// fallback (no workspace): bsearch + fp32, one wave per row
__global__ __launch_bounds__(256)
void aspect_fallback(const int* __restrict__ user_id,
                     const int* __restrict__ a_ids, const int* __restrict__ a_seg, int Ta,
                     const int* __restrict__ c_ids, const int* __restrict__ c_seg, int Tc,
                     const float* __restrict__ user_factors,
                     const float4* __restrict__ ef4,
                     const float* __restrict__ relation_k,
                     float* __restrict__ out)
{
    const int b    = blockIdx.x * 4 + (threadIdx.x >> 6);
    const int lane = threadIdx.x & 63;
    const int g = lane >> 4, k = lane & 15;

    const int uid = user_id[b];
    const float4 u4 = reinterpret_cast<const float4*>(user_factors)[uid * 16 + k];

    float p0 = 0.f, p1 = 0.f, p2 = 0.f;
    {
        const float uv[4] = {u4.x, u4.y, u4.z, u4.w};
#pragma unroll
        for (int j = 0; j < 4; ++j) {
            const int row = 4 * k + j;
            p0 += uv[j] * relation_k[row * 3 + 0];
            p1 += uv[j] * relation_k[row * 3 + 1];
            p2 += uv[j] * relation_k[row * 3 + 2];
        }
    }
#pragma unroll
    for (int off = 1; off <= 8; off <<= 1) {
        p0 += __shfl_xor(p0, off, 64);
        p1 += __shfl_xor(p1, off, 64);
        p2 += __shfl_xor(p2, off, 64);
    }
    float l0 = p0 > 0.f ? p0 : SLOPE * p0;
    float l1 = p1 > 0.f ? p1 : SLOPE * p1;
    float l2 = p2 > 0.f ? p2 : SLOPE * p2;
    const float m  = fmaxf(l0, fmaxf(l1, l2));
    const float e0 = __expf(l0 - m), e1 = __expf(l1 - m), e2 = __expf(l2 - m);
    const float inv = 1.0f / (e0 + e1 + e2);
    const float s0 = e0 * inv, s1 = e1 * inv, s2 = e2 * inv;

    auto gd = [&](const int* __restrict__ ids, int s, int e) -> float {
        float ax = 0.f, ay = 0.f, az = 0.f, aw = 0.f;
        int t = s;
        for (; t + 4 <= e; t += 4) {
            const float4 v0 = ef4[ids[t + g] * 16 + k];
            ax += v0.x; ay += v0.y; az += v0.z; aw += v0.w;
        }
        if (t + g < e) {
            const float4 v0 = ef4[ids[t + g] * 16 + k];
            ax += v0.x; ay += v0.y; az += v0.z; aw += v0.w;
        }
        return reduce64(ax * u4.x + ay * u4.y + az * u4.z + aw * u4.w);
    };

    const int sa = lower_bound(a_seg, Ta, b), ea = lower_bound(a_seg, Ta, b + 1);
    const int sc = lower_bound(c_seg, Tc, b), ec = lower_bound(c_seg, Tc, b + 1);
    const float c_a = gd(a_ids, sa, ea) / (float)(ea - sa);
    const float c_c = gd(c_ids, sc, ec) / (float)(ec - sc);
    const float pred = (c_a * s0 + c_c * s1) / (s0 + s1);

    if (lane == 0) {
        out[b]          = pred;
        out[4 * NB + b] = c_a;
        out[5 * NB + b] = c_c;
    }
    if (lane < 3) {
        const float sv = (lane == 0) ? s0 : ((lane == 1) ? s1 : s2);
        out[NB + 3 * b + lane] = sv;
    }
}

extern "C" void kernel_launch(void* const* d_in, const int* in_sizes, int n_in,
                              void* d_out, int out_size, void* d_ws, size_t ws_size,
                              hipStream_t stream) {
    const int*   user_id        = (const int*)d_in[0];
    const int*   artists_ids    = (const int*)d_in[1];
    const int*   artists_seg    = (const int*)d_in[2];
    const int*   categories_ids = (const int*)d_in[3];
    const int*   categories_seg = (const int*)d_in[4];
    const float* user_factors   = (const float*)d_in[5];
    const float* entity_factors = (const float*)d_in[6];
    const float* relation_k     = (const float*)d_in[7];
    float* out = (float*)d_out;

    const int Ta = in_sizes[1];
    const int Tc = in_sizes[3];
    const int n_ent_elems = in_sizes[6];    // N_ENTITY * D
    const int n2 = n_ent_elems / 2;

    // layout: [f16 table at ws+0 (rows 128B-aligned)] [offs_a] [offs_c]
    const size_t table_bytes = (size_t)n_ent_elems * 2;
    const size_t offs_bytes  = (size_t)2 * (NB + 1) * sizeof(int);

    if (ws_size >= table_bytes + offs_bytes) {
        unsigned* efh    = (unsigned*)d_ws;
        int*      offs_a = (int*)((unsigned char*)d_ws + table_bytes);
        int*      offs_c = offs_a + (NB + 1);
        int prep_n = n2 > Ta ? n2 : Ta;
        if (Tc > prep_n) prep_n = Tc;
        prepass<<<(prep_n + 255) / 256, 256, 0, stream>>>(
            (const float2*)entity_factors, efh, n2,
            artists_seg, Ta, offs_a,
            categories_seg, Tc, offs_c);
        aspect_deep<<<NB / 4, 256, 0, stream>>>(user_id,
            artists_ids, offs_a, categories_ids, offs_c,
            user_factors, (const uint4*)efh, relation_k, out);
    } else {
        aspect_fallback<<<NB / 4, 256, 0, stream>>>(user_id,
            artists_ids, artists_seg, Ta,
            categories_ids, categories_seg, Tc,
            user_factors, (const float4*)entity_factors, relation_k, out);
    }
}

// Round 12
// 72.499 us; speedup vs baseline: 1.3711x; 1.0814x over previous
//
#include <hip/hip_runtime.h>

#define NB 65536
#define D 64
#define SLOPE 0.2f
#define GA 10   // max artists groups: ceil(79/8)
#define GC 3    // max categories groups: ceil(19/8)

typedef _Float16 h2f __attribute__((ext_vector_type(2)));

__device__ __forceinline__ h2f as_h2(unsigned x) {
    union { unsigned u; h2f h; } v; v.u = x; return v.h;
}

struct UH { h2f h0, h1, h2, h3; };

__device__ __forceinline__ float dot8(uint4 w, const UH& u, float acc) {
#if __has_builtin(__builtin_amdgcn_fdot2)
    acc = __builtin_amdgcn_fdot2(as_h2(w.x), u.h0, acc, false);
    acc = __builtin_amdgcn_fdot2(as_h2(w.y), u.h1, acc, false);
    acc = __builtin_amdgcn_fdot2(as_h2(w.z), u.h2, acc, false);
    acc = __builtin_amdgcn_fdot2(as_h2(w.w), u.h3, acc, false);
#else
    h2f t0 = as_h2(w.x) * u.h0 + as_h2(w.y) * u.h1;
    h2f t1 = as_h2(w.z) * u.h2 + as_h2(w.w) * u.h3;
    acc += (float)t0.x + (float)t0.y + (float)t1.x + (float)t1.y;
#endif
    return acc;
}

__device__ __forceinline__ float reduce8(float v) {
#pragma unroll
    for (int off = 1; off <= 4; off <<= 1)
        v += __shfl_xor(v, off, 64);
    return v;
}
__device__ __forceinline__ float reduce64(float v) {
#pragma unroll
    for (int off = 1; off <= 32; off <<= 1)
        v += __shfl_xor(v, off, 64);
    return v;
}

__device__ __forceinline__ int lower_bound(const int* __restrict__ seg, int n, int key) {
    int lo = 0, hi = n;
    while (lo < hi) {
        int mid = (lo + hi) >> 1;
        if (seg[mid] < key) lo = mid + 1;
        else hi = mid;
    }
    return lo;
}

// merged pre-pass: fp32 -> f16 table convert (table at ws+0, rows 128B-aligned) + offsets
__global__ __launch_bounds__(256)
void prepass(const float2* __restrict__ ef2, unsigned* __restrict__ eh, int n2,
             const int* __restrict__ a_seg, int Ta, int* __restrict__ offs_a,
             const int* __restrict__ c_seg, int Tc, int* __restrict__ offs_c)
{
    const int t = blockIdx.x * blockDim.x + threadIdx.x;
    if (t < n2) {
        float2 v = ef2[t];
        h2f h = { (_Float16)v.x, (_Float16)v.y };
        union { h2f h; unsigned u; } cv; cv.h = h;
        eh[t] = cv.u;
    }
    if (t < Ta) {
        int s = a_seg[t];
        if (t == 0) offs_a[0] = 0;
        else if (a_seg[t - 1] != s) offs_a[s] = t;
        if (t == Ta - 1) offs_a[s + 1] = Ta;
    }
    if (t < Tc) {
        int s = c_seg[t];
        if (t == 0) offs_c[0] = 0;
        else if (c_seg[t - 1] != s) offs_c[s] = t;
        if (t == Tc - 1) offs_c[s + 1] = Tc;
    }
}

// one wave per row; straight-line batch: ALL id loads -> softmax VALU -> ALL gathers -> dots.
// sched_barrier(0) fences pin the clusters so the compiler cannot sink loads to uses.
// Clamped indices make every load valid; dup groups hit the same line (broadcast-coalesced).
__global__ __launch_bounds__(256, 5)
void aspect_batch(const int* __restrict__ user_id,
                  const int* __restrict__ a_ids, const int* __restrict__ offs_a,
                  const int* __restrict__ c_ids, const int* __restrict__ offs_c,
                  const float* __restrict__ user_factors,
                  const uint4* __restrict__ efh,    // f16 table, 8 uint4 per row
                  const float* __restrict__ relation_k,
                  float* __restrict__ out)
{
    const int b    = blockIdx.x * 4 + (threadIdx.x >> 6);
    const int lane = threadIdx.x & 63;
    const int r = lane >> 3;     // row subgroup 0..7
    const int c = lane & 7;      // dim chunk 0..7 (dims 8c..8c+7)

    const int uid = user_id[b];
    const float4 ua = reinterpret_cast<const float4*>(user_factors)[uid * 16 + 2 * c];
    const float4 ub = reinterpret_cast<const float4*>(user_factors)[uid * 16 + 2 * c + 1];

    const int sa = offs_a[b], ea = offs_a[b + 1];
    const int sc = offs_c[b], ec = offs_c[b + 1];
    const int na = ea - sa, nc = ec - sc;

    // ---- batch 1: ALL id loads, unconditional (clamped) ----
    int ida[GA], idc[GC];
#pragma unroll
    for (int g = 0; g < GA; ++g)
        ida[g] = a_ids[sa + min(8 * g + r, na - 1)];
#pragma unroll
    for (int g = 0; g < GC; ++g)
        idc[g] = c_ids[sc + min(8 * g + r, nc - 1)];
    __builtin_amdgcn_sched_barrier(0);

    // ---- softmax VALU covers id-load latency ----
    float p0 = 0.f, p1 = 0.f, p2 = 0.f;
    {
        const float uv[8] = {ua.x, ua.y, ua.z, ua.w, ub.x, ub.y, ub.z, ub.w};
#pragma unroll
        for (int j = 0; j < 8; ++j) {
            const int row = 8 * c + j;
            p0 += uv[j] * relation_k[row * 3 + 0];
            p1 += uv[j] * relation_k[row * 3 + 1];
            p2 += uv[j] * relation_k[row * 3 + 2];
        }
    }
    float l0 = reduce8(p0), l1 = reduce8(p1), l2 = reduce8(p2);
    l0 = l0 > 0.f ? l0 : SLOPE * l0;
    l1 = l1 > 0.f ? l1 : SLOPE * l1;
    l2 = l2 > 0.f ? l2 : SLOPE * l2;
    const float m  = fmaxf(l0, fmaxf(l1, l2));
    const float e0 = __expf(l0 - m);
    const float e1 = __expf(l1 - m);
    const float e2 = __expf(l2 - m);
    const float inv = 1.0f / (e0 + e1 + e2);
    const float s0 = e0 * inv, s1 = e1 * inv, s2 = e2 * inv;

    UH uh;
    uh.h0 = h2f{ (_Float16)ua.x, (_Float16)ua.y };
    uh.h1 = h2f{ (_Float16)ua.z, (_Float16)ua.w };
    uh.h2 = h2f{ (_Float16)ub.x, (_Float16)ub.y };
    uh.h3 = h2f{ (_Float16)ub.z, (_Float16)ub.w };
    __builtin_amdgcn_sched_barrier(0);

    // ---- batch 2: ALL row gathers issued back-to-back (13 in flight) ----
    uint4 wa[GA], wc[GC];
#pragma unroll
    for (int g = 0; g < GA; ++g)
        wa[g] = efh[(unsigned)ida[g] * 8 + c];
#pragma unroll
    for (int g = 0; g < GC; ++g)
        wc[g] = efh[(unsigned)idc[g] * 8 + c];
    __builtin_amdgcn_sched_barrier(0);

    // ---- batch 3: dots, tail/dup lanes zeroed ----
    float accA = 0.f, accC = 0.f;
#pragma unroll
    for (int g = 0; g < GA; ++g) {
        const float d = dot8(wa[g], uh, 0.f);
        accA += (8 * g + r < na) ? d : 0.f;
    }
#pragma unroll
    for (int g = 0; g < GC; ++g) {
        const float d = dot8(wc[g], uh, 0.f);
        accC += (8 * g + r < nc) ? d : 0.f;
    }

    // overflow safety (dead for this generator: na<=79, nc<=19)
    for (int i = 8 * GA + r; i < na; i += 8)
        accA = dot8(efh[(unsigned)a_ids[sa + i] * 8 + c], uh, accA);
    for (int i = 8 * GC + r; i < nc; i += 8)
        accC = dot8(efh[(unsigned)c_ids[sc + i] * 8 + c], uh, accC);

    const float c_a = reduce64(accA) / (float)na;
    const float c_c = reduce64(accC) / (float)nc;

    const float pred = (c_a * s0 + c_c * s1) / (s0 + s1);

    if (lane == 0) {
        out[b]          = pred;
        out[4 * NB + b] = c_a;
        out[5 * NB + b] = c_c;
    }
    if (lane < 3) {
        const float sv = (lane == 0) ? s0 : ((lane == 1) ? s1 : s2);
        out[NB + 3 * b + lane] = sv;
    }
}

// fallback (no workspace): bsearch + fp32, one wave per row
__global__ __launch_bounds__(256)
void aspect_fallback(const int* __restrict__ user_id,
                     const int* __restrict__ a_ids, const int* __restrict__ a_seg, int Ta,
                     const int* __restrict__ c_ids, const int* __restrict__ c_seg, int Tc,
                     const float* __restrict__ user_factors,
                     const float4* __restrict__ ef4,
                     const float* __restrict__ relation_k,
                     float* __restrict__ out)
{
    const int b    = blockIdx.x * 4 + (threadIdx.x >> 6);
    const int lane = threadIdx.x & 63;
    const int g = lane >> 4, k = lane & 15;

    const int uid = user_id[b];
    const float4 u4 = reinterpret_cast<const float4*>(user_factors)[uid * 16 + k];

    float p0 = 0.f, p1 = 0.f, p2 = 0.f;
    {
        const float uv[4] = {u4.x, u4.y, u4.z, u4.w};
#pragma unroll
        for (int j = 0; j < 4; ++j) {
            const int row = 4 * k + j;
            p0 += uv[j] * relation_k[row * 3 + 0];
            p1 += uv[j] * relation_k[row * 3 + 1];
            p2 += uv[j] * relation_k[row * 3 + 2];
        }
    }
#pragma unroll
    for (int off = 1; off <= 8; off <<= 1) {
        p0 += __shfl_xor(p0, off, 64);
        p1 += __shfl_xor(p1, off, 64);
        p2 += __shfl_xor(p2, off, 64);
    }
    float l0 = p0 > 0.f ? p0 : SLOPE * p0;
    float l1 = p1 > 0.f ? p1 : SLOPE * p1;
    float l2 = p2 > 0.f ? p2 : SLOPE * p2;
    const float m  = fmaxf(l0, fmaxf(l1, l2));
    const float e0 = __expf(l0 - m), e1 = __expf(l1 - m), e2 = __expf(l2 - m);
    const float inv = 1.0f / (e0 + e1 + e2);
    const float s0 = e0 * inv, s1 = e1 * inv, s2 = e2 * inv;

    auto gd = [&](const int* __restrict__ ids, int s, int e) -> float {
        float ax = 0.f, ay = 0.f, az = 0.f, aw = 0.f;
        int t = s;
        for (; t + 4 <= e; t += 4) {
            const float4 v0 = ef4[ids[t + g] * 16 + k];
            ax += v0.x; ay += v0.y; az += v0.z; aw += v0.w;
        }
        if (t + g < e) {
            const float4 v0 = ef4[ids[t + g] * 16 + k];
            ax += v0.x; ay += v0.y; az += v0.z; aw += v0.w;
        }
        return reduce64(ax * u4.x + ay * u4.y + az * u4.z + aw * u4.w);
    };

    const int sa = lower_bound(a_seg, Ta, b), ea = lower_bound(a_seg, Ta, b + 1);
    const int sc = lower_bound(c_seg, Tc, b), ec = lower_bound(c_seg, Tc, b + 1);
    const float c_a = gd(a_ids, sa, ea) / (float)(ea - sa);
    const float c_c = gd(c_ids, sc, ec) / (float)(ec - sc);
    const float pred = (c_a * s0 + c_c * s1) / (s0 + s1);

    if (lane == 0) {
        out[b]          = pred;
        out[4 * NB + b] = c_a;
        out[5 * NB + b] = c_c;
    }
    if (lane < 3) {
        const float sv = (lane == 0) ? s0 : ((lane == 1) ? s1 : s2);
        out[NB + 3 * b + lane] = sv;
    }
}

extern "C" void kernel_launch(void* const* d_in, const int* in_sizes, int n_in,
                              void* d_out, int out_size, void* d_ws, size_t ws_size,
                              hipStream_t stream) {
    const int*   user_id        = (const int*)d_in[0];
    const int*   artists_ids    = (const int*)d_in[1];
    const int*   artists_seg    = (const int*)d_in[2];
    const int*   categories_ids = (const int*)d_in[3];
    const int*   categories_seg = (const int*)d_in[4];
    const float* user_factors   = (const float*)d_in[5];
    const float* entity_factors = (const float*)d_in[6];
    const float* relation_k     = (const float*)d_in[7];
    float* out = (float*)d_out;

    const int Ta = in_sizes[1];
    const int Tc = in_sizes[3];
    const int n_ent_elems = in_sizes[6];    // N_ENTITY * D
    const int n2 = n_ent_elems / 2;

    // layout: [f16 table at ws+0 (rows 128B-aligned)] [offs_a] [offs_c]
    const size_t table_bytes = (size_t)n_ent_elems * 2;
    const size_t offs_bytes  = (size_t)2 * (NB + 1) * sizeof(int);

    if (ws_size >= table_bytes + offs_bytes) {
        unsigned* efh    = (unsigned*)d_ws;
        int*      offs_a = (int*)((unsigned char*)d_ws + table_bytes);
        int*      offs_c = offs_a + (NB + 1);
        int prep_n = n2 > Ta ? n2 : Ta;
        if (Tc > prep_n) prep_n = Tc;
        prepass<<<(prep_n + 255) / 256, 256, 0, stream>>>(
            (const float2*)entity_factors, efh, n2,
            artists_seg, Ta, offs_a,
            categories_seg, Tc, offs_c);
        aspect_batch<<<NB / 4, 256, 0, stream>>>(user_id,
            artists_ids, offs_a, categories_ids, offs_c,
            user_factors, (const uint4*)efh, relation_k, out);
    } else {
        aspect_fallback<<<NB / 4, 256, 0, stream>>>(user_id,
            artists_ids, artists_seg, Ta,
            categories_ids, categories_seg, Tc,
            user_factors, (const float4*)entity_factors, relation_k, out);
    }
}